// Round 1
// baseline (894.841 us; speedup 1.0000x reference)
//
#include <hip/hip_runtime.h>
#include <math.h>

// AutoCorrelation (Autoformer) on MI355X.
// B*H=256, L=2048, E=64, fp32. FFT-based: per (b,h,e) series:
//   corr = IFFT( FFT(Q) * conj(FFT(K)) ), top-15 lags, softmax, 15-tap circular
//   gather of V. Q,K packed as one complex FFT (z = Q + iK).
// Pipeline: transpose QK -> ZT[bh][e][l] ; kfft -> (w,d) pairs ;
//           transpose V -> VT (in d_out) ; gather -> OT ; transpose back.
// ws usage: ZT 256MiB (reused for OT) + Wt 1MiB + Dl 1MiB  (~258 MiB total)

#define LEN   2048
#define BH    256
#define NE    64
#define NSER  (BH * NE)   // 16384
#define TOPK  15

__device__ __forceinline__ int IDX(int i) { return i + (i >> 4); }  // LDS anti-conflict pad

__device__ __forceinline__ void cmulf(float xr, float xi, float yr, float yi,
                                      float& zr, float& zi) {
  zr = xr * yr - xi * yi;
  zi = xr * yi + xi * yr;
}

// twiddle W_2048^idx = e^{-2*pi*i*idx/2048} -> (c, s) = (cos th, sin th), th = -2pi idx/2048
__device__ __forceinline__ void sincos_tw(int idx, float& c, float& s) {
  float ang = (float)idx * (-6.283185307179586f / 2048.0f);
  __sincosf(ang, &s, &c);
}

// 8-point DFT in registers. INV=false: W8 = e^{-2pi i/8}; INV=true: conjugated.
template <bool INV>
__device__ __forceinline__ void dft8(float* xr, float* xi) {
  const float sg = INV ? -1.f : 1.f;
  const float c = 0.70710678118654752440f;
  // even (0,2,4,6)
  float s0r = xr[0] + xr[4], s0i = xi[0] + xi[4];
  float s1r = xr[0] - xr[4], s1i = xi[0] - xi[4];
  float s2r = xr[2] + xr[6], s2i = xi[2] + xi[6];
  float s3r = xr[2] - xr[6], s3i = xi[2] - xi[6];
  float E0r = s0r + s2r, E0i = s0i + s2i;
  float E2r = s0r - s2r, E2i = s0i - s2i;
  float E1r = s1r + sg * s3i, E1i = s1i - sg * s3r;
  float E3r = s1r - sg * s3i, E3i = s1i + sg * s3r;
  // odd (1,3,5,7)
  float u0r = xr[1] + xr[5], u0i = xi[1] + xi[5];
  float u1r = xr[1] - xr[5], u1i = xi[1] - xi[5];
  float u2r = xr[3] + xr[7], u2i = xi[3] + xi[7];
  float u3r = xr[3] - xr[7], u3i = xi[3] - xi[7];
  float O0r = u0r + u2r, O0i = u0i + u2i;
  float O2r = u0r - u2r, O2i = u0i - u2i;
  float O1r = u1r + sg * u3i, O1i = u1i - sg * u3r;
  float O3r = u1r - sg * u3i, O3i = u1i + sg * u3r;
  // odd * W8^j
  float G0r = O0r, G0i = O0i;
  float G1r, G1i; cmulf(O1r, O1i, c, -sg * c, G1r, G1i);
  float G2r = sg * O2i, G2i = -sg * O2r;
  float G3r, G3i; cmulf(O3r, O3i, -c, -sg * c, G3r, G3i);
  xr[0] = E0r + G0r; xi[0] = E0i + G0i;
  xr[1] = E1r + G1r; xi[1] = E1i + G1i;
  xr[2] = E2r + G2r; xi[2] = E2i + G2i;
  xr[3] = E3r + G3r; xi[3] = E3i + G3i;
  xr[4] = E0r - G0r; xi[4] = E0i - G0i;
  xr[5] = E1r - G1r; xi[5] = E1i - G1i;
  xr[6] = E2r - G2r; xi[6] = E2i - G2i;
  xr[7] = E3r - G3r; xi[7] = E3i - G3i;
}

template <bool INV>
__device__ __forceinline__ void dft4(float* xr, float* xi) {
  const float sg = INV ? -1.f : 1.f;
  float s0r = xr[0] + xr[2], s0i = xi[0] + xi[2];
  float s1r = xr[0] - xr[2], s1i = xi[0] - xi[2];
  float s2r = xr[1] + xr[3], s2i = xi[1] + xi[3];
  float s3r = xr[1] - xr[3], s3i = xi[1] - xi[3];
  xr[0] = s0r + s2r;        xi[0] = s0i + s2i;
  xr[1] = s1r + sg * s3i;   xi[1] = s1i - sg * s3r;
  xr[2] = s0r - s2r;        xi[2] = s0i - s2i;
  xr[3] = s1r - sg * s3i;   xi[3] = s1i + sg * s3r;
}

// Generic Stockham radix-8 stage: in -> out, stride s (sLog=log2 s).
// Reads at t+256r (stride-1 across lanes, conflict-free). 256 threads, N=2048.
template <bool INV>
__device__ __forceinline__ void stage8_mid(const float* inr, const float* ini,
                                           float* outr, float* outi,
                                           int s, int sLog, int t) {
  float ar[8], ai[8];
#pragma unroll
  for (int r = 0; r < 8; ++r) {
    int a = t + 256 * r;
    ar[r] = inr[IDX(a)]; ai[r] = ini[IDX(a)];
  }
  dft8<INV>(ar, ai);
  int q = t & (s - 1), p = t >> sLog;
  int ob = q + 8 * s * p;   // out index = ob + s*j
  int tb = s * p;           // twiddle index = tb*j  (< 2048 always)
#pragma unroll
  for (int j = 0; j < 8; ++j) {
    float c_, s_;
    sincos_tw(tb * j, c_, s_);
    if (INV) s_ = -s_;
    float zr, zi; cmulf(ar[j], ai[j], c_, s_, zr, zi);
    int o = ob + s * j;
    outr[IDX(o)] = zr; outi[IDX(o)] = zi;
  }
}

// ---------------- transpose kernels (64x64 LDS tiles) ----------------

__global__ __launch_bounds__(256) void ktrans_qk(const float* __restrict__ Q,
                                                 const float* __restrict__ K,
                                                 float2* __restrict__ ZT) {
  int bh = blockIdx.x >> 5, lt = blockIdx.x & 31, l0 = lt * 64;
  __shared__ float sq[64][65], sk[64][65];
  int col = threadIdx.x & 63, r4 = threadIdx.x >> 6;
  const float* Qb = Q + ((size_t)bh * LEN + l0) * NE;
  const float* Kb = K + ((size_t)bh * LEN + l0) * NE;
#pragma unroll
  for (int it = 0; it < 16; ++it) {
    int row = it * 4 + r4;
    sq[row][col] = Qb[row * NE + col];
    sk[row][col] = Kb[row * NE + col];
  }
  __syncthreads();
  float2* Zb = ZT + (size_t)bh * NE * LEN + l0;
#pragma unroll
  for (int it = 0; it < 16; ++it) {
    int e = it * 4 + r4;
    float2 z; z.x = sq[col][e]; z.y = sk[col][e];
    Zb[(size_t)e * LEN + col] = z;
  }
}

__global__ __launch_bounds__(256) void ktrans_v(const float* __restrict__ src,
                                                float* __restrict__ dst) {
  int bh = blockIdx.x >> 5, lt = blockIdx.x & 31, l0 = lt * 64;
  __shared__ float sT[64][65];
  int col = threadIdx.x & 63, r4 = threadIdx.x >> 6;
  const float* Sb = src + ((size_t)bh * LEN + l0) * NE;
#pragma unroll
  for (int it = 0; it < 16; ++it) {
    int row = it * 4 + r4;
    sT[row][col] = Sb[row * NE + col];
  }
  __syncthreads();
  float* Db = dst + (size_t)bh * NE * LEN + l0;
#pragma unroll
  for (int it = 0; it < 16; ++it) {
    int e = it * 4 + r4;
    Db[(size_t)e * LEN + col] = sT[col][e];
  }
}

__global__ __launch_bounds__(256) void ktrans_o(const float* __restrict__ OT,
                                                float* __restrict__ out) {
  int bh = blockIdx.x >> 5, lt = blockIdx.x & 31, l0 = lt * 64;
  __shared__ float sT[64][65];
  int col = threadIdx.x & 63, r4 = threadIdx.x >> 6;
  const float* Sb = OT + (size_t)bh * NE * LEN + l0;
#pragma unroll
  for (int it = 0; it < 16; ++it) {
    int e = it * 4 + r4;
    sT[e][col] = Sb[(size_t)e * LEN + col];
  }
  __syncthreads();
  float* Ob = out + ((size_t)bh * LEN + l0) * NE;
#pragma unroll
  for (int it = 0; it < 16; ++it) {
    int row = it * 4 + r4;
    Ob[row * NE + col] = sT[col][row];
  }
}

// ---------------- FFT + corr + topk + softmax ----------------

__global__ __launch_bounds__(256) void kfft(const float2* __restrict__ ZT,
                                            float* __restrict__ Wt,
                                            int* __restrict__ Dl) {
  __shared__ float Ar_[2176], Ai_[2176], Br_[2176], Bi_[2176];
  __shared__ float topv[16]; __shared__ int topd[16];
  __shared__ float redv[4]; __shared__ int redi[4];
  const int t = threadIdx.x;
  const int series = blockIdx.x;
  const float2* z = ZT + (size_t)series * LEN;

  // ---- forward FFT of z = Q + iK : stages A<-global, A->B, B->A, A->B ----
  {  // stage 1 (s=1) directly from global
    float ar[8], ai[8];
#pragma unroll
    for (int r = 0; r < 8; ++r) {
      float2 v = z[t + 256 * r];
      ar[r] = v.x; ai[r] = v.y;
    }
    dft8<false>(ar, ai);
#pragma unroll
    for (int j = 0; j < 8; ++j) {
      float c_, s_;
      sincos_tw(t * j, c_, s_);
      float zr, zi; cmulf(ar[j], ai[j], c_, s_, zr, zi);
      int o = 8 * t + j;
      Ar_[IDX(o)] = zr; Ai_[IDX(o)] = zi;
    }
  }
  __syncthreads();
  stage8_mid<false>(Ar_, Ai_, Br_, Bi_, 8, 3, t);
  __syncthreads();
  stage8_mid<false>(Br_, Bi_, Ar_, Ai_, 64, 6, t);
  __syncthreads();
  {  // stage 4: radix-4, s=512, p=0 (no twiddle): A->B
#pragma unroll
    for (int h = 0; h < 2; ++h) {
      int u = t + 256 * h;
      float xr[4], xi[4];
#pragma unroll
      for (int r = 0; r < 4; ++r) {
        int a = u + 512 * r;
        xr[r] = Ar_[IDX(a)]; xi[r] = Ai_[IDX(a)];
      }
      dft4<false>(xr, xi);
#pragma unroll
      for (int j = 0; j < 4; ++j) {
        int o = u + 512 * j;
        Br_[IDX(o)] = xr[j]; Bi_[IDX(o)] = xi[j];
      }
    }
  }
  __syncthreads();

  // ---- C[f] = X[f] * conj(Y[f]) from packed spectrum: B -> A ----
#pragma unroll
  for (int r = 0; r < 8; ++r) {
    int f = t + 256 * r;
    int m = (LEN - f) & (LEN - 1);
    float zfr = Br_[IDX(f)], zfi = Bi_[IDX(f)];
    float zmr = Br_[IDX(m)], zmi = Bi_[IDX(m)];
    float Xr = 0.5f * (zfr + zmr), Xi = 0.5f * (zfi - zmi);
    float Yr = 0.5f * (zfi + zmi), Yi = -0.5f * (zfr - zmr);
    float Cr = Xr * Yr + Xi * Yi;
    float Ci = Xi * Yr - Xr * Yi;
    Ar_[IDX(f)] = Cr; Ai_[IDX(f)] = Ci;
  }
  __syncthreads();

  // ---- inverse FFT: A->B, B->A, A->B, then final radix-4 into registers ----
  stage8_mid<true>(Ar_, Ai_, Br_, Bi_, 1, 0, t);
  __syncthreads();
  stage8_mid<true>(Br_, Bi_, Ar_, Ai_, 8, 3, t);
  __syncthreads();
  stage8_mid<true>(Ar_, Ai_, Br_, Bi_, 64, 6, t);
  __syncthreads();
  float rv[8]; int rix[8];
#pragma unroll
  for (int h = 0; h < 2; ++h) {
    int u = t + 256 * h;
    float xr[4], xi[4];
#pragma unroll
    for (int r = 0; r < 4; ++r) {
      int a = u + 512 * r;
      xr[r] = Br_[IDX(a)]; xi[r] = Bi_[IDX(a)];
    }
    dft4<true>(xr, xi);
#pragma unroll
    for (int j = 0; j < 4; ++j) {
      rv[h * 4 + j] = xr[j];           // corr * 2048 (unnormalized)
      rix[h * 4 + j] = u + 512 * j;    // lag index
    }
  }

  // ---- top-15 (register-resident tournament) ----
  for (int it = 0; it < TOPK; ++it) {
    float bv = rv[0]; int bi_ = rix[0];
#pragma unroll
    for (int k = 1; k < 8; ++k) {
      bool btr = (rv[k] > bv) || (rv[k] == bv && rix[k] < bi_);
      if (btr) { bv = rv[k]; bi_ = rix[k]; }
    }
#pragma unroll
    for (int off = 32; off >= 1; off >>= 1) {
      float ov = __shfl_xor(bv, off);
      int oi = __shfl_xor(bi_, off);
      bool btr = (ov > bv) || (ov == bv && oi < bi_);
      if (btr) { bv = ov; bi_ = oi; }
    }
    if ((t & 63) == 0) { redv[t >> 6] = bv; redi[t >> 6] = bi_; }
    __syncthreads();
    if (t == 0) {
#pragma unroll
      for (int wv = 1; wv < 4; ++wv) {
        bool btr = (redv[wv] > bv) || (redv[wv] == bv && redi[wv] < bi_);
        if (btr) { bv = redv[wv]; bi_ = redi[wv]; }
      }
      topv[it] = bv; topd[it] = bi_;
    }
    __syncthreads();
    int widx = topd[it];
#pragma unroll
    for (int k = 0; k < 8; ++k)
      if (rix[k] == widx) rv[k] = -INFINITY;
  }

  // ---- softmax over the 15 (scaled by 1/2048 to undo missing IFFT norm) ----
  if (t < TOPK) {
    const float scl = 1.0f / 2048.0f;
    float vmax = topv[0];
    float ssum = 0.f;
#pragma unroll
    for (int i = 0; i < TOPK; ++i) ssum += expf((topv[i] - vmax) * scl);
    float wgt = expf((topv[t] - vmax) * scl) / ssum;
    Wt[(size_t)series * 16 + t] = wgt;
    Dl[(size_t)series * 16 + t] = topd[t];
  }
}

// ---------------- weighted circular gather ----------------

__global__ __launch_bounds__(256) void kgather(const float* __restrict__ VT,
                                               const float* __restrict__ Wt,
                                               const int* __restrict__ Dl,
                                               float* __restrict__ OT) {
  __shared__ float v[LEN];
  const int t = threadIdx.x;
  const int series = blockIdx.x;
  const float4* src = (const float4*)(VT + (size_t)series * LEN);
  float4* vv = (float4*)v;
#pragma unroll
  for (int i = 0; i < 2; ++i) vv[t + 256 * i] = src[t + 256 * i];
  float w[TOPK]; int d[TOPK];
#pragma unroll
  for (int i = 0; i < TOPK; ++i) {
    w[i] = Wt[(size_t)series * 16 + i];
    d[i] = Dl[(size_t)series * 16 + i];
  }
  __syncthreads();
  float* dst = OT + (size_t)series * LEN;
#pragma unroll
  for (int r = 0; r < 8; ++r) {
    int l = t + 256 * r;
    float acc = 0.f;
#pragma unroll
    for (int i = 0; i < TOPK; ++i) acc += w[i] * v[(l + d[i]) & (LEN - 1)];
    dst[l] = acc;
  }
}

extern "C" void kernel_launch(void* const* d_in, const int* in_sizes, int n_in,
                              void* d_out, int out_size, void* d_ws, size_t ws_size,
                              hipStream_t stream) {
  const float* Q = (const float*)d_in[0];
  const float* K = (const float*)d_in[1];
  const float* V = (const float*)d_in[2];
  float* out = (float*)d_out;
  char* ws = (char*)d_ws;

  const size_t ZT_BYTES = (size_t)NSER * LEN * sizeof(float2);  // 268435456
  float2* ZT = (float2*)ws;
  float* Wt = (float*)(ws + ZT_BYTES);
  int* Dl = (int*)(ws + ZT_BYTES + (size_t)NSER * 16 * sizeof(float));
  float* OT = (float*)ws;   // reuse ZT region after kfft consumed it
  float* VT = out;          // d_out used as scratch for transposed V

  ktrans_qk<<<BH * 32, 256, 0, stream>>>(Q, K, ZT);
  kfft<<<NSER, 256, 0, stream>>>(ZT, Wt, Dl);
  ktrans_v<<<BH * 32, 256, 0, stream>>>(V, VT);
  kgather<<<NSER, 256, 0, stream>>>(VT, Wt, Dl, OT);
  ktrans_o<<<BH * 32, 256, 0, stream>>>(OT, out);
}

// Round 2
// 885.664 us; speedup vs baseline: 1.0104x; 1.0104x over previous
//
#include <hip/hip_runtime.h>
#include <math.h>

// AutoCorrelation (Autoformer) on MI355X.
// B*H=256, L=2048, E=64, fp32. FFT-based: per (b,h,e) series:
//   corr = IFFT( FFT(Q) * conj(FFT(K)) ), top-15 lags, softmax, 15-tap circular
//   gather of V. Q,K packed as one complex FFT (z = Q + iK).
// Pipeline: transpose QK -> ZT[bh][e][l] ; kfft -> (w,d) pairs ;
//           transpose V -> VT (in d_out) ; gather -> OT ; transpose back.
// ws usage: ZT 256MiB (reused for OT) + Wt 1MiB + Dl 1MiB  (~258 MiB total)
//
// R1 changes (theory: kfft was occupancy+barrier bound, transposes scalar):
//  - kfft: single in-place LDS buffer (17.9KB, was 34.8KB) -> 8 blocks/CU
//  - kfft: per-wave barrier-free top-15 + single-wave merge + reg softmax
//  - kfft: pair-based spectrum step (f and 2048-f together)
//  - transposes: float4 global loads AND stores on both sides

#define LEN   2048
#define BH    256
#define NE    64
#define NSER  (BH * NE)   // 16384
#define TOPK  15
#define NINF  (-INFINITY)

__device__ __forceinline__ int IDX(int i) { return i + (i >> 4); }  // LDS anti-conflict pad

__device__ __forceinline__ void cmulf(float xr, float xi, float yr, float yi,
                                      float& zr, float& zi) {
  zr = xr * yr - xi * yi;
  zi = xr * yi + xi * yr;
}

// twiddle W_2048^idx: (c,s) = (cos th, sin th), th = -2pi idx/2048
__device__ __forceinline__ void sincos_tw(int idx, float& c, float& s) {
  float ang = (float)idx * (-6.283185307179586f / 2048.0f);
  __sincosf(ang, &s, &c);
}

template <bool INV>
__device__ __forceinline__ void dft8(float* xr, float* xi) {
  const float sg = INV ? -1.f : 1.f;
  const float c = 0.70710678118654752440f;
  float s0r = xr[0] + xr[4], s0i = xi[0] + xi[4];
  float s1r = xr[0] - xr[4], s1i = xi[0] - xi[4];
  float s2r = xr[2] + xr[6], s2i = xi[2] + xi[6];
  float s3r = xr[2] - xr[6], s3i = xi[2] - xi[6];
  float E0r = s0r + s2r, E0i = s0i + s2i;
  float E2r = s0r - s2r, E2i = s0i - s2i;
  float E1r = s1r + sg * s3i, E1i = s1i - sg * s3r;
  float E3r = s1r - sg * s3i, E3i = s1i + sg * s3r;
  float u0r = xr[1] + xr[5], u0i = xi[1] + xi[5];
  float u1r = xr[1] - xr[5], u1i = xi[1] - xi[5];
  float u2r = xr[3] + xr[7], u2i = xi[3] + xi[7];
  float u3r = xr[3] - xr[7], u3i = xi[3] - xi[7];
  float O0r = u0r + u2r, O0i = u0i + u2i;
  float O2r = u0r - u2r, O2i = u0i - u2i;
  float O1r = u1r + sg * u3i, O1i = u1i - sg * u3r;
  float O3r = u1r - sg * u3i, O3i = u1i + sg * u3r;
  float G0r = O0r, G0i = O0i;
  float G1r, G1i; cmulf(O1r, O1i, c, -sg * c, G1r, G1i);
  float G2r = sg * O2i, G2i = -sg * O2r;
  float G3r, G3i; cmulf(O3r, O3i, -c, -sg * c, G3r, G3i);
  xr[0] = E0r + G0r; xi[0] = E0i + G0i;
  xr[1] = E1r + G1r; xi[1] = E1i + G1i;
  xr[2] = E2r + G2r; xi[2] = E2i + G2i;
  xr[3] = E3r + G3r; xi[3] = E3i + G3i;
  xr[4] = E0r - G0r; xi[4] = E0i - G0i;
  xr[5] = E1r - G1r; xi[5] = E1i - G1i;
  xr[6] = E2r - G2r; xi[6] = E2i - G2i;
  xr[7] = E3r - G3r; xi[7] = E3i - G3i;
}

template <bool INV>
__device__ __forceinline__ void dft4(float* xr, float* xi) {
  const float sg = INV ? -1.f : 1.f;
  float s0r = xr[0] + xr[2], s0i = xi[0] + xi[2];
  float s1r = xr[0] - xr[2], s1i = xi[0] - xi[2];
  float s2r = xr[1] + xr[3], s2i = xi[1] + xi[3];
  float s3r = xr[1] - xr[3], s3i = xi[1] - xi[3];
  xr[0] = s0r + s2r;        xi[0] = s0i + s2i;
  xr[1] = s1r + sg * s3i;   xi[1] = s1i - sg * s3r;
  xr[2] = s0r - s2r;        xi[2] = s0i - s2i;
  xr[3] = s1r - sg * s3i;   xi[3] = s1i + sg * s3r;
}

// In-place Stockham radix-8 stage on single LDS buffer.
// Reads t+256r (stride-1), BARRIER, scatter writes, BARRIER.
template <bool INV>
__device__ __forceinline__ void stage8_ip(float* Re, float* Im,
                                          int s, int sLog, int t) {
  float ar[8], ai[8];
#pragma unroll
  for (int r = 0; r < 8; ++r) {
    int a = t + 256 * r;
    ar[r] = Re[IDX(a)]; ai[r] = Im[IDX(a)];
  }
  __syncthreads();
  dft8<INV>(ar, ai);
  int q = t & (s - 1), p = t >> sLog;
  int ob = q + 8 * s * p;
  int tb = s * p;
#pragma unroll
  for (int j = 0; j < 8; ++j) {
    float c_, s_;
    sincos_tw(tb * j, c_, s_);
    if (INV) s_ = -s_;
    float zr, zi; cmulf(ar[j], ai[j], c_, s_, zr, zi);
    int o = ob + s * j;
    Re[IDX(o)] = zr; Im[IDX(o)] = zi;
  }
  __syncthreads();
}

// ---------------- transpose kernels (64x64 LDS tiles, float4 global) --------

__global__ __launch_bounds__(256) void ktrans_qk(const float* __restrict__ Q,
                                                 const float* __restrict__ K,
                                                 float2* __restrict__ ZT) {
  int bh = blockIdx.x >> 5, l0 = (blockIdx.x & 31) * 64;
  __shared__ float sq[64][65], sk[64][65];
  int t = threadIdx.x;
  const float4* Qb = (const float4*)(Q + ((size_t)bh * LEN + l0) * NE);
  const float4* Kb = (const float4*)(K + ((size_t)bh * LEN + l0) * NE);
  int x = t & 15, c4 = x * 4;
#pragma unroll
  for (int it = 0; it < 4; ++it) {
    int row = (t >> 4) + it * 16;
    float4 q4 = Qb[row * 16 + x];
    float4 k4 = Kb[row * 16 + x];
    sq[row][c4 + 0] = q4.x; sq[row][c4 + 1] = q4.y;
    sq[row][c4 + 2] = q4.z; sq[row][c4 + 3] = q4.w;
    sk[row][c4 + 0] = k4.x; sk[row][c4 + 1] = k4.y;
    sk[row][c4 + 2] = k4.z; sk[row][c4 + 3] = k4.w;
  }
  __syncthreads();
  float2* Zb = ZT + (size_t)bh * NE * LEN + l0;
  int l2 = (t & 31) * 2;
#pragma unroll
  for (int it = 0; it < 8; ++it) {
    int e = (t >> 5) + it * 8;
    float4 o;
    o.x = sq[l2][e];     o.y = sk[l2][e];
    o.z = sq[l2 + 1][e]; o.w = sk[l2 + 1][e];
    *(float4*)&Zb[(size_t)e * LEN + l2] = o;
  }
}

__global__ __launch_bounds__(256) void ktrans_v(const float* __restrict__ src,
                                                float* __restrict__ dst) {
  int bh = blockIdx.x >> 5, l0 = (blockIdx.x & 31) * 64;
  __shared__ float sT[64][65];
  int t = threadIdx.x;
  const float4* Sb = (const float4*)(src + ((size_t)bh * LEN + l0) * NE);
  int x = t & 15, c4 = x * 4;
#pragma unroll
  for (int it = 0; it < 4; ++it) {
    int row = (t >> 4) + it * 16;
    float4 v4 = Sb[row * 16 + x];
    sT[row][c4 + 0] = v4.x; sT[row][c4 + 1] = v4.y;
    sT[row][c4 + 2] = v4.z; sT[row][c4 + 3] = v4.w;
  }
  __syncthreads();
  float* Db = dst + (size_t)bh * NE * LEN + l0;
  int l4 = x * 4;
#pragma unroll
  for (int it = 0; it < 4; ++it) {
    int e = (t >> 4) + it * 16;
    float4 o;
    o.x = sT[l4 + 0][e]; o.y = sT[l4 + 1][e];
    o.z = sT[l4 + 2][e]; o.w = sT[l4 + 3][e];
    *(float4*)&Db[(size_t)e * LEN + l4] = o;
  }
}

__global__ __launch_bounds__(256) void ktrans_o(const float* __restrict__ OT,
                                                float* __restrict__ out) {
  int bh = blockIdx.x >> 5, l0 = (blockIdx.x & 31) * 64;
  __shared__ float sT[64][65];  // [e][l]
  int t = threadIdx.x;
  const float* Sb = OT + (size_t)bh * NE * LEN + l0;
  int x = t & 15, l4 = x * 4;
#pragma unroll
  for (int it = 0; it < 4; ++it) {
    int e = (t >> 4) + it * 16;
    float4 v4 = *(const float4*)&Sb[(size_t)e * LEN + l4];
    sT[e][l4 + 0] = v4.x; sT[e][l4 + 1] = v4.y;
    sT[e][l4 + 2] = v4.z; sT[e][l4 + 3] = v4.w;
  }
  __syncthreads();
  float* Ob = out + ((size_t)bh * LEN + l0) * NE;
  int e4 = x * 4;
#pragma unroll
  for (int it = 0; it < 4; ++it) {
    int row = (t >> 4) + it * 16;
    float4 o;
    o.x = sT[e4 + 0][row]; o.y = sT[e4 + 1][row];
    o.z = sT[e4 + 2][row]; o.w = sT[e4 + 3][row];
    *(float4*)&Ob[row * NE + e4] = o;
  }
}

// ---------------- FFT + corr + topk + softmax (single in-place buffer) ------

__global__ __launch_bounds__(256, 8) void kfft(const float2* __restrict__ ZT,
                                               float* __restrict__ Wt,
                                               int* __restrict__ Dl) {
  __shared__ float Re[2176], Im[2176];
  __shared__ float mv[64]; __shared__ int mi[64];
  const int t = threadIdx.x;
  const int wv = t >> 6, ln = t & 63;
  const float2* z = ZT + (size_t)blockIdx.x * LEN;

  // ---- forward stage 1 (s=1): global -> LDS scatter ----
  {
    float ar[8], ai[8];
#pragma unroll
    for (int r = 0; r < 8; ++r) {
      float2 v = z[t + 256 * r];
      ar[r] = v.x; ai[r] = v.y;
    }
    dft8<false>(ar, ai);
#pragma unroll
    for (int j = 0; j < 8; ++j) {
      float c_, s_;
      sincos_tw(t * j, c_, s_);
      float zr, zi; cmulf(ar[j], ai[j], c_, s_, zr, zi);
      int o = 8 * t + j;
      Re[IDX(o)] = zr; Im[IDX(o)] = zi;
    }
  }
  __syncthreads();
  stage8_ip<false>(Re, Im, 8, 3, t);
  stage8_ip<false>(Re, Im, 64, 6, t);
  // ---- forward radix-4 (s=512, no twiddle): thread-private slots ----
#pragma unroll
  for (int h = 0; h < 2; ++h) {
    int u = t + 256 * h;
    float xr[4], xi[4];
#pragma unroll
    for (int r = 0; r < 4; ++r) {
      int a = u + 512 * r;
      xr[r] = Re[IDX(a)]; xi[r] = Im[IDX(a)];
    }
    dft4<false>(xr, xi);
#pragma unroll
    for (int j = 0; j < 4; ++j) {
      int o = u + 512 * j;
      Re[IDX(o)] = xr[j]; Im[IDX(o)] = xi[j];
    }
  }
  __syncthreads();

  // ---- spectrum: C = X*conj(Y), pair-based (f in [0,1024), m = 2048-f) ----
  {
    float zfr[4], zfi[4], zmr[4], zmi[4];
#pragma unroll
    for (int r = 0; r < 4; ++r) {
      int f = t + 256 * r;           // 0..1023
      int m = (LEN - f) & (LEN - 1);
      zfr[r] = Re[IDX(f)]; zfi[r] = Im[IDX(f)];
      zmr[r] = Re[IDX(m)]; zmi[r] = Im[IDX(m)];
    }
    float e1r = 0.f, e1i = 0.f;      // z[1024] handled by thread 0
    if (t == 0) { e1r = Re[IDX(1024)]; e1i = Im[IDX(1024)]; }
    __syncthreads();
#pragma unroll
    for (int r = 0; r < 4; ++r) {
      int f = t + 256 * r;
      int m = (LEN - f) & (LEN - 1);
      // C[f]
      float Xr = 0.5f * (zfr[r] + zmr[r]), Xi = 0.5f * (zfi[r] - zmi[r]);
      float Yr = 0.5f * (zfi[r] + zmi[r]), Yi = -0.5f * (zfr[r] - zmr[r]);
      Re[IDX(f)] = Xr * Yr + Xi * Yi;
      Im[IDX(f)] = Xi * Yr - Xr * Yi;
      // C[m] (m==f only when f==0; same value recomputed, benign)
      float Xr2 = 0.5f * (zmr[r] + zfr[r]), Xi2 = 0.5f * (zmi[r] - zfi[r]);
      float Yr2 = 0.5f * (zfi[r] + zmi[r]), Yi2 = -0.5f * (zmr[r] - zfr[r]);
      Re[IDX(m)] = Xr2 * Yr2 + Xi2 * Yi2;
      Im[IDX(m)] = Xi2 * Yr2 - Xr2 * Yi2;
    }
    if (t == 0) {  // self-paired bin 1024: X = Re z, Y = Im z
      Re[IDX(1024)] = e1r * e1i;
      Im[IDX(1024)] = 0.f;
    }
  }
  __syncthreads();

  // ---- inverse FFT: 3 in-place radix-8 stages + final radix-4 into regs ----
  stage8_ip<true>(Re, Im, 1, 0, t);
  stage8_ip<true>(Re, Im, 8, 3, t);
  stage8_ip<true>(Re, Im, 64, 6, t);
  float rv[8];
#pragma unroll
  for (int h = 0; h < 2; ++h) {
    int u = t + 256 * h;
    float xr[4], xi[4];
#pragma unroll
    for (int r = 0; r < 4; ++r) {
      int a = u + 512 * r;
      xr[r] = Re[IDX(a)]; xi[r] = Im[IDX(a)];
    }
    dft4<true>(xr, xi);
#pragma unroll
    for (int j = 0; j < 4; ++j) rv[h * 4 + j] = xr[j];  // corr * 2048
  }
  // slot k holds lag idx = t + 256*(k>>2) + 512*(k&3)

  // ---- per-wave top-15 (barrier-free shfl tournaments) ----
  for (int it = 0; it < TOPK; ++it) {
    float bv = rv[0]; int bidx = t;
#pragma unroll
    for (int k = 1; k < 8; ++k) {
      int ik = t + 256 * (k >> 2) + 512 * (k & 3);
      bool btr = (rv[k] > bv) || (rv[k] == bv && ik < bidx);
      if (btr) { bv = rv[k]; bidx = ik; }
    }
#pragma unroll
    for (int off = 32; off >= 1; off >>= 1) {
      float ov = __shfl_xor(bv, off);
      int oi = __shfl_xor(bidx, off);
      bool btr = (ov > bv) || (ov == bv && oi < bidx);
      if (btr) { bv = ov; bidx = oi; }
    }
    if (ln == 0) { mv[wv * 16 + it] = bv; mi[wv * 16 + it] = bidx; }
    int d = bidx - t;  // winner's slot offset if it's ours
#pragma unroll
    for (int k = 0; k < 8; ++k) {
      int ck = 256 * (k >> 2) + 512 * (k & 3);
      if (d == ck) rv[k] = NINF;
    }
  }
  __syncthreads();

  // ---- single-wave merge of 4x15 + softmax, all in registers ----
  if (wv == 0) {
    float v = ((ln & 15) < TOPK) ? mv[ln] : NINF;
    int ix = ((ln & 15) < TOPK) ? mi[ln] : 0;
    float myv = NINF; int myi = 0;
    for (int it = 0; it < TOPK; ++it) {
      float bv = v; int bidx = ix;
#pragma unroll
      for (int off = 32; off >= 1; off >>= 1) {
        float ov = __shfl_xor(bv, off);
        int oi = __shfl_xor(bidx, off);
        bool btr = (ov > bv) || (ov == bv && oi < bidx);
        if (btr) { bv = ov; bidx = oi; }
      }
      if (ln == it) { myv = bv; myi = bidx; }
      if (ix == bidx) v = NINF;
    }
    const float scl = 1.0f / 2048.0f;
    float vmax = __shfl(myv, 0);  // first selected == max
    float e = (ln < TOPK) ? expf((myv - vmax) * scl) : 0.f;
    float ssum = e;
#pragma unroll
    for (int off = 1; off < 16; off <<= 1) ssum += __shfl_xor(ssum, off);
    if (ln < TOPK) {
      Wt[(size_t)blockIdx.x * 16 + ln] = e / ssum;
      Dl[(size_t)blockIdx.x * 16 + ln] = myi;
    }
  }
}

// ---------------- weighted circular gather ----------------

__global__ __launch_bounds__(256) void kgather(const float* __restrict__ VT,
                                               const float* __restrict__ Wt,
                                               const int* __restrict__ Dl,
                                               float* __restrict__ OT) {
  __shared__ float v[LEN];
  const int t = threadIdx.x;
  const int series = blockIdx.x;
  const float4* src = (const float4*)(VT + (size_t)series * LEN);
  float4* vv = (float4*)v;
#pragma unroll
  for (int i = 0; i < 2; ++i) vv[t + 256 * i] = src[t + 256 * i];
  float w[TOPK]; int d[TOPK];
#pragma unroll
  for (int i = 0; i < TOPK; ++i) {
    w[i] = Wt[(size_t)series * 16 + i];
    d[i] = Dl[(size_t)series * 16 + i];
  }
  __syncthreads();
  float* dst = OT + (size_t)series * LEN;
#pragma unroll
  for (int r = 0; r < 8; ++r) {
    int l = t + 256 * r;
    float acc = 0.f;
#pragma unroll
    for (int i = 0; i < TOPK; ++i) acc += w[i] * v[(l + d[i]) & (LEN - 1)];
    dst[l] = acc;
  }
}

extern "C" void kernel_launch(void* const* d_in, const int* in_sizes, int n_in,
                              void* d_out, int out_size, void* d_ws, size_t ws_size,
                              hipStream_t stream) {
  const float* Q = (const float*)d_in[0];
  const float* K = (const float*)d_in[1];
  const float* V = (const float*)d_in[2];
  float* out = (float*)d_out;
  char* ws = (char*)d_ws;

  const size_t ZT_BYTES = (size_t)NSER * LEN * sizeof(float2);  // 268435456
  float2* ZT = (float2*)ws;
  float* Wt = (float*)(ws + ZT_BYTES);
  int* Dl = (int*)(ws + ZT_BYTES + (size_t)NSER * 16 * sizeof(float));
  float* OT = (float*)ws;   // reuse ZT region after kfft consumed it
  float* VT = out;          // d_out used as scratch for transposed V

  ktrans_qk<<<BH * 32, 256, 0, stream>>>(Q, K, ZT);
  kfft<<<NSER, 256, 0, stream>>>(ZT, Wt, Dl);
  ktrans_v<<<BH * 32, 256, 0, stream>>>(V, VT);
  kgather<<<NSER, 256, 0, stream>>>(VT, Wt, Dl, OT);
  ktrans_o<<<BH * 32, 256, 0, stream>>>(OT, out);
}

// Round 3
// 859.011 us; speedup vs baseline: 1.0417x; 1.0310x over previous
//
#include <hip/hip_runtime.h>
#include <math.h>

// AutoCorrelation (Autoformer) on MI355X.
// B*H=256, L=2048, E=64, fp32. FFT-based: per (b,h,e) series:
//   corr = IFFT( FFT(Q) * conj(FFT(K)) ), top-15 lags, softmax, 15-tap circular
//   gather of V. Q,K packed as one complex FFT (z = Q + iK).
// Pipeline R3: ktrans_qk -> ZT[bh][e][l] ; kfft -> (w,d) ;
//              ktrans_v -> VT (aliases ZT in ws) ; kgather_out -> out directly
// ws: ZT/VT 256MiB + Wt 1MiB + Dl 1MiB (~258 MiB)
//
// R3 changes (R2 post-mortem: (256,8) forced VGPR=32 -> 1.26GB scratch spill):
//  - kfft launch_bounds (256,6): no spill-level pressure, keeps occupancy
//  - kfft LDS: interleaved float2 + (c>>4) pad -> ds b64, half the LDS ops
//  - twiddles: 1 sincos + complex recurrence per stage (was 8 sincos)
//  - topk: per-lane Batcher sort-8 + head-pop tournament (no per-round rescan)
//  - kgather writes out[bh][l][e] directly (XCD-grouped by bh so L2 merges
//    the stride-256B scatter); ktrans_o eliminated (-268MB round trip)

#define LEN   2048
#define BH    256
#define NE    64
#define NSER  (BH * NE)   // 16384
#define TOPK  15
#define NINF  (-INFINITY)

__device__ __forceinline__ int PC(int c) { return c + (c >> 4); }  // complex-unit pad

// twiddle W_2048^idx: (c,s) = (cos th, sin th), th = -2pi idx/2048
__device__ __forceinline__ void sincos_tw(int idx, float& c, float& s) {
  float ang = (float)idx * (-6.283185307179586f / 2048.0f);
  __sincosf(ang, &s, &c);
}

template <bool INV>
__device__ __forceinline__ void dft8(float* xr, float* xi) {
  const float sg = INV ? -1.f : 1.f;
  const float c = 0.70710678118654752440f;
  float s0r = xr[0] + xr[4], s0i = xi[0] + xi[4];
  float s1r = xr[0] - xr[4], s1i = xi[0] - xi[4];
  float s2r = xr[2] + xr[6], s2i = xi[2] + xi[6];
  float s3r = xr[2] - xr[6], s3i = xi[2] - xi[6];
  float E0r = s0r + s2r, E0i = s0i + s2i;
  float E2r = s0r - s2r, E2i = s0i - s2i;
  float E1r = s1r + sg * s3i, E1i = s1i - sg * s3r;
  float E3r = s1r - sg * s3i, E3i = s1i + sg * s3r;
  float u0r = xr[1] + xr[5], u0i = xi[1] + xi[5];
  float u1r = xr[1] - xr[5], u1i = xi[1] - xi[5];
  float u2r = xr[3] + xr[7], u2i = xi[3] + xi[7];
  float u3r = xr[3] - xr[7], u3i = xi[3] - xi[7];
  float O0r = u0r + u2r, O0i = u0i + u2i;
  float O2r = u0r - u2r, O2i = u0i - u2i;
  float O1r = u1r + sg * u3i, O1i = u1i - sg * u3r;
  float O3r = u1r - sg * u3i, O3i = u1i + sg * u3r;
  float G0r = O0r, G0i = O0i;
  float G1r = O1r * c + O1i * (sg * c), G1i = O1i * c - O1r * (sg * c);
  float G2r = sg * O2i, G2i = -sg * O2r;
  float G3r = -O3r * c + O3i * (sg * c), G3i = -O3i * c - O3r * (sg * c);
  xr[0] = E0r + G0r; xi[0] = E0i + G0i;
  xr[1] = E1r + G1r; xi[1] = E1i + G1i;
  xr[2] = E2r + G2r; xi[2] = E2i + G2i;
  xr[3] = E3r + G3r; xi[3] = E3i + G3i;
  xr[4] = E0r - G0r; xi[4] = E0i - G0i;
  xr[5] = E1r - G1r; xi[5] = E1i - G1i;
  xr[6] = E2r - G2r; xi[6] = E2i - G2i;
  xr[7] = E3r - G3r; xi[7] = E3i - G3i;
}

template <bool INV>
__device__ __forceinline__ void dft4(float* xr, float* xi) {
  const float sg = INV ? -1.f : 1.f;
  float s0r = xr[0] + xr[2], s0i = xi[0] + xi[2];
  float s1r = xr[0] - xr[2], s1i = xi[0] - xi[2];
  float s2r = xr[1] + xr[3], s2i = xi[1] + xi[3];
  float s3r = xr[1] - xr[3], s3i = xi[1] - xi[3];
  xr[0] = s0r + s2r;        xi[0] = s0i + s2i;
  xr[1] = s1r + sg * s3i;   xi[1] = s1i - sg * s3r;
  xr[2] = s0r - s2r;        xi[2] = s0i - s2i;
  xr[3] = s1r - sg * s3i;   xi[3] = s1i + sg * s3r;
}

// In-place Stockham radix-8 stage on interleaved complex LDS buffer.
// Twiddles: one sincos for W^(s*p), then complex recurrence for powers.
template <bool INV>
__device__ __forceinline__ void stage8_ip(float2* CB, int s, int sLog, int t) {
  float ar[8], ai[8];
#pragma unroll
  for (int r = 0; r < 8; ++r) {
    float2 v = CB[PC(t + 256 * r)];
    ar[r] = v.x; ai[r] = v.y;
  }
  __syncthreads();
  dft8<INV>(ar, ai);
  int q = t & (s - 1), p = t >> sLog;
  int ob = q + 8 * s * p;
  float c1, s1; sincos_tw(s * p, c1, s1);
  if (INV) s1 = -s1;
  CB[PC(ob)] = make_float2(ar[0], ai[0]);
  float wc = c1, wsn = s1;
#pragma unroll
  for (int j = 1; j < 8; ++j) {
    float zr = ar[j] * wc - ai[j] * wsn;
    float zi = ar[j] * wsn + ai[j] * wc;
    CB[PC(ob + s * j)] = make_float2(zr, zi);
    if (j < 7) {
      float nc = wc * c1 - wsn * s1;
      wsn = wc * s1 + wsn * c1;
      wc = nc;
    }
  }
  __syncthreads();
}

// ---------------- transpose kernels (64x64 LDS tiles, float4 global) --------

__global__ __launch_bounds__(256) void ktrans_qk(const float* __restrict__ Q,
                                                 const float* __restrict__ K,
                                                 float2* __restrict__ ZT) {
  int bh = blockIdx.x >> 5, l0 = (blockIdx.x & 31) * 64;
  __shared__ float sq[64][65], sk[64][65];
  int t = threadIdx.x;
  const float4* Qb = (const float4*)(Q + ((size_t)bh * LEN + l0) * NE);
  const float4* Kb = (const float4*)(K + ((size_t)bh * LEN + l0) * NE);
  int x = t & 15, c4 = x * 4;
#pragma unroll
  for (int it = 0; it < 4; ++it) {
    int row = (t >> 4) + it * 16;
    float4 q4 = Qb[row * 16 + x];
    float4 k4 = Kb[row * 16 + x];
    sq[row][c4 + 0] = q4.x; sq[row][c4 + 1] = q4.y;
    sq[row][c4 + 2] = q4.z; sq[row][c4 + 3] = q4.w;
    sk[row][c4 + 0] = k4.x; sk[row][c4 + 1] = k4.y;
    sk[row][c4 + 2] = k4.z; sk[row][c4 + 3] = k4.w;
  }
  __syncthreads();
  float2* Zb = ZT + (size_t)bh * NE * LEN + l0;
  int l2 = (t & 31) * 2;
#pragma unroll
  for (int it = 0; it < 8; ++it) {
    int e = (t >> 5) + it * 8;
    float4 o;
    o.x = sq[l2][e];     o.y = sk[l2][e];
    o.z = sq[l2 + 1][e]; o.w = sk[l2 + 1][e];
    *(float4*)&Zb[(size_t)e * LEN + l2] = o;
  }
}

__global__ __launch_bounds__(256) void ktrans_v(const float* __restrict__ src,
                                                float* __restrict__ dst) {
  int bh = blockIdx.x >> 5, l0 = (blockIdx.x & 31) * 64;
  __shared__ float sT[64][65];
  int t = threadIdx.x;
  const float4* Sb = (const float4*)(src + ((size_t)bh * LEN + l0) * NE);
  int x = t & 15, c4 = x * 4;
#pragma unroll
  for (int it = 0; it < 4; ++it) {
    int row = (t >> 4) + it * 16;
    float4 v4 = Sb[row * 16 + x];
    sT[row][c4 + 0] = v4.x; sT[row][c4 + 1] = v4.y;
    sT[row][c4 + 2] = v4.z; sT[row][c4 + 3] = v4.w;
  }
  __syncthreads();
  float* Db = dst + (size_t)bh * NE * LEN + l0;
  int l4 = x * 4;
#pragma unroll
  for (int it = 0; it < 4; ++it) {
    int e = (t >> 4) + it * 16;
    float4 o;
    o.x = sT[l4 + 0][e]; o.y = sT[l4 + 1][e];
    o.z = sT[l4 + 2][e]; o.w = sT[l4 + 3][e];
    *(float4*)&Db[(size_t)e * LEN + l4] = o;
  }
}

// ---------------- FFT + corr + topk + softmax ----------------

__global__ __launch_bounds__(256, 6) void kfft(const float2* __restrict__ ZT,
                                               float* __restrict__ Wt,
                                               int* __restrict__ Dl) {
  __shared__ float2 CB[2176];            // 2048 complex + pad (17.4 KB)
  __shared__ float mv[64]; __shared__ int mi[64];
  const int t = threadIdx.x;
  const int wv = t >> 6, ln = t & 63;
  const float2* z = ZT + (size_t)blockIdx.x * LEN;

  // ---- forward stage 1 (s=1): global -> LDS scatter ----
  {
    float ar[8], ai[8];
#pragma unroll
    for (int r = 0; r < 8; ++r) {
      float2 v = z[t + 256 * r];
      ar[r] = v.x; ai[r] = v.y;
    }
    dft8<false>(ar, ai);
    float c1, s1; sincos_tw(t, c1, s1);
    CB[PC(8 * t)] = make_float2(ar[0], ai[0]);
    float wc = c1, wsn = s1;
#pragma unroll
    for (int j = 1; j < 8; ++j) {
      float zr = ar[j] * wc - ai[j] * wsn;
      float zi = ar[j] * wsn + ai[j] * wc;
      CB[PC(8 * t + j)] = make_float2(zr, zi);
      if (j < 7) {
        float nc = wc * c1 - wsn * s1;
        wsn = wc * s1 + wsn * c1;
        wc = nc;
      }
    }
  }
  __syncthreads();
  stage8_ip<false>(CB, 8, 3, t);
  stage8_ip<false>(CB, 64, 6, t);
  // ---- forward radix-4 (s=512, no twiddle): thread-private slots ----
#pragma unroll
  for (int h = 0; h < 2; ++h) {
    int u = t + 256 * h;
    float xr[4], xi[4];
#pragma unroll
    for (int r = 0; r < 4; ++r) {
      float2 v = CB[PC(u + 512 * r)];
      xr[r] = v.x; xi[r] = v.y;
    }
    dft4<false>(xr, xi);
#pragma unroll
    for (int j = 0; j < 4; ++j) CB[PC(u + 512 * j)] = make_float2(xr[j], xi[j]);
  }
  __syncthreads();

  // ---- spectrum: C = X*conj(Y), pair-based (f in [0,1024), m = 2048-f) ----
  {
    float2 zf[4], zm[4];
#pragma unroll
    for (int r = 0; r < 4; ++r) {
      int f = t + 256 * r;
      int m = (LEN - f) & (LEN - 1);
      zf[r] = CB[PC(f)]; zm[r] = CB[PC(m)];
    }
    float2 e1 = make_float2(0.f, 0.f);
    if (t == 0) e1 = CB[PC(1024)];
    __syncthreads();
#pragma unroll
    for (int r = 0; r < 4; ++r) {
      int f = t + 256 * r;
      int m = (LEN - f) & (LEN - 1);
      float Xr = 0.5f * (zf[r].x + zm[r].x), Xi = 0.5f * (zf[r].y - zm[r].y);
      float Yr = 0.5f * (zf[r].y + zm[r].y), Yi = -0.5f * (zf[r].x - zm[r].x);
      CB[PC(f)] = make_float2(Xr * Yr + Xi * Yi, Xi * Yr - Xr * Yi);
      float Xr2 = 0.5f * (zm[r].x + zf[r].x), Xi2 = 0.5f * (zm[r].y - zf[r].y);
      float Yr2 = 0.5f * (zf[r].y + zm[r].y), Yi2 = -0.5f * (zm[r].x - zf[r].x);
      CB[PC(m)] = make_float2(Xr2 * Yr2 + Xi2 * Yi2, Xi2 * Yr2 - Xr2 * Yi2);
    }
    if (t == 0) CB[PC(1024)] = make_float2(e1.x * e1.y, 0.f);
  }
  __syncthreads();

  // ---- inverse FFT: 3 in-place radix-8 stages + final radix-4 into regs ----
  stage8_ip<true>(CB, 1, 0, t);
  stage8_ip<true>(CB, 8, 3, t);
  stage8_ip<true>(CB, 64, 6, t);
  float rv[8]; int ri[8];
#pragma unroll
  for (int h = 0; h < 2; ++h) {
    int u = t + 256 * h;
    float xr[4], xi[4];
#pragma unroll
    for (int r = 0; r < 4; ++r) {
      float2 v = CB[PC(u + 512 * r)];
      xr[r] = v.x; xi[r] = v.y;
    }
    dft4<true>(xr, xi);
#pragma unroll
    for (int j = 0; j < 4; ++j) {
      rv[h * 4 + j] = xr[j];          // corr * 2048
      ri[h * 4 + j] = u + 512 * j;    // lag index
    }
  }

  // ---- per-lane Batcher sort-8 (desc by value) ----
#define CE(i, j) { bool sw = rv[i] < rv[j];                                   \
    float tv = sw ? rv[j] : rv[i]; rv[j] = sw ? rv[i] : rv[j]; rv[i] = tv;    \
    int tx = sw ? ri[j] : ri[i];  ri[j] = sw ? ri[i] : ri[j];  ri[i] = tx; }
  CE(0,1) CE(2,3) CE(4,5) CE(6,7)
  CE(0,2) CE(1,3) CE(4,6) CE(5,7)
  CE(1,2) CE(5,6)
  CE(0,4) CE(1,5) CE(2,6) CE(3,7)
  CE(2,4) CE(3,5)
  CE(1,2) CE(3,4) CE(5,6)
#undef CE

  // ---- per-wave top-15: head-pop tournament ----
  for (int it = 0; it < TOPK; ++it) {
    float bv = rv[0]; int bidx = ri[0];
#pragma unroll
    for (int off = 32; off >= 1; off >>= 1) {
      float ov = __shfl_xor(bv, off);
      int oi = __shfl_xor(bidx, off);
      bool btr = (ov > bv) || (ov == bv && oi < bidx);
      if (btr) { bv = ov; bidx = oi; }
    }
    if (ln == 0) { mv[wv * 16 + it] = bv; mi[wv * 16 + it] = bidx; }
    if (bidx == ri[0]) {  // this lane's head won (indices globally unique)
#pragma unroll
      for (int k = 0; k < 7; ++k) { rv[k] = rv[k + 1]; ri[k] = ri[k + 1]; }
      rv[7] = NINF;
    }
  }
  __syncthreads();

  // ---- single-wave merge of 4x15 + softmax, all in registers ----
  if (wv == 0) {
    float v = ((ln & 15) < TOPK) ? mv[ln] : NINF;
    int ix = ((ln & 15) < TOPK) ? mi[ln] : 0;
    float myv = NINF; int myi = 0;
    for (int it = 0; it < TOPK; ++it) {
      float bv = v; int bidx = ix;
#pragma unroll
      for (int off = 32; off >= 1; off >>= 1) {
        float ov = __shfl_xor(bv, off);
        int oi = __shfl_xor(bidx, off);
        bool btr = (ov > bv) || (ov == bv && oi < bidx);
        if (btr) { bv = ov; bidx = oi; }
      }
      if (ln == it) { myv = bv; myi = bidx; }
      if (ix == bidx) v = NINF;
    }
    const float scl = 1.0f / 2048.0f;
    float vmax = __shfl(myv, 0);  // first selected == max
    float e = (ln < TOPK) ? expf((myv - vmax) * scl) : 0.f;
    float ssum = e;
#pragma unroll
    for (int off = 1; off < 16; off <<= 1) ssum += __shfl_xor(ssum, off);
    if (ln < TOPK) {
      Wt[(size_t)blockIdx.x * 16 + ln] = e / ssum;
      Dl[(size_t)blockIdx.x * 16 + ln] = myi;
    }
  }
}

// -------- weighted circular gather, writing out[bh][l][e] directly ---------
// Block w -> series s = (w&7)*2048 + (w>>3): all 64 e-blocks of one bh land on
// one XCD (w%8 const) within a ~512-dispatch window, so the stride-256B 4B
// scatter stores merge into full lines in that XCD's L2.

__global__ __launch_bounds__(256) void kgather_out(const float* __restrict__ VT,
                                                   const float* __restrict__ Wt,
                                                   const int* __restrict__ Dl,
                                                   float* __restrict__ out) {
  const int w = blockIdx.x;
  const int s = (w & 7) * 2048 + (w >> 3);
  const int bh = s >> 6, e = s & 63;
  __shared__ float v[LEN];
  const int t = threadIdx.x;
  const float4* src = (const float4*)(VT + (size_t)s * LEN);
  float4* vv = (float4*)v;
#pragma unroll
  for (int i = 0; i < 2; ++i) vv[t + 256 * i] = src[t + 256 * i];
  float wgt[TOPK]; int d[TOPK];
#pragma unroll
  for (int i = 0; i < TOPK; ++i) {
    wgt[i] = Wt[(size_t)s * 16 + i];
    d[i] = Dl[(size_t)s * 16 + i];
  }
  __syncthreads();
  float* dst = out + ((size_t)bh * LEN) * NE + e;
#pragma unroll
  for (int r = 0; r < 8; ++r) {
    int l = t + 256 * r;
    float acc = 0.f;
#pragma unroll
    for (int i = 0; i < TOPK; ++i) acc += wgt[i] * v[(l + d[i]) & (LEN - 1)];
    dst[(size_t)l * NE] = acc;
  }
}

extern "C" void kernel_launch(void* const* d_in, const int* in_sizes, int n_in,
                              void* d_out, int out_size, void* d_ws, size_t ws_size,
                              hipStream_t stream) {
  const float* Q = (const float*)d_in[0];
  const float* K = (const float*)d_in[1];
  const float* V = (const float*)d_in[2];
  float* out = (float*)d_out;
  char* ws = (char*)d_ws;

  const size_t ZT_BYTES = (size_t)NSER * LEN * sizeof(float2);  // 256 MiB
  float2* ZT = (float2*)ws;
  float* Wt = (float*)(ws + ZT_BYTES);
  int* Dl = (int*)(ws + ZT_BYTES + (size_t)NSER * 16 * sizeof(float));
  float* VT = (float*)ws;  // aliases ZT; safe: ktrans_v runs after kfft

  ktrans_qk<<<BH * 32, 256, 0, stream>>>(Q, K, ZT);
  kfft<<<NSER, 256, 0, stream>>>(ZT, Wt, Dl);
  ktrans_v<<<BH * 32, 256, 0, stream>>>(V, VT);
  kgather_out<<<NSER, 256, 0, stream>>>(VT, Wt, Dl, out);
}

// Round 5
// 794.759 us; speedup vs baseline: 1.1259x; 1.0808x over previous
//
#include <hip/hip_runtime.h>
#include <math.h>

// AutoCorrelation (Autoformer) on MI355X.
// B*H=256, L=2048, E=64, fp32. FFT-based: per (b,h,e) series:
//   corr = IFFT( FFT(Q) * conj(FFT(K)) ), top-15 lags, softmax, 15-tap circular
//   gather of V. Q,K packed as one complex FFT (z = Q + iK).
// Pipeline R4: ktrans_qk -> ZT[bh][e][l] ; kfft -> (w,d) ;
//   ktrans_v V->VT (d_out scratch) ; kgather VT->OT (ws) ; ktrans_o OT->out.
//
// R4 post-mortem-driven changes (resubmitted after R4 broker timeout):
//  - kfft: NO min-wave launch_bounds. R2 (256,8)->VGPR32, 1.26GB spill;
//    R3 (256,6)->VGPR40, 355MB spill (WRITE_SIZE 182MB vs 2MB true output).
//    R1 unbounded: VGPR60, zero spill. Let the allocator breathe.
//  - revert kgather_out scatter (cost +110us vs coalesced pair): back to
//    kgather (coalesced OT write) + ktrans_o (float4 both sides).
//  - twiddles via v_sin/v_cos revolutions form (arg in (-1,0], no range
//    reduction) instead of __sincosf.

#define LEN   2048
#define BH    256
#define NE    64
#define NSER  (BH * NE)   // 16384
#define TOPK  15
#define NINF  (-INFINITY)

__device__ __forceinline__ int PC(int c) { return c + (c >> 4); }  // complex-unit pad

// twiddle W_2048^idx = (cos, sin) of -2*pi*idx/2048, idx in [0, 2048)
__device__ __forceinline__ void sincos_tw(int idx, float& c, float& s) {
#if __has_builtin(__builtin_amdgcn_sinf) && __has_builtin(__builtin_amdgcn_cosf)
  float rev = (float)idx * (-1.0f / 2048.0f);   // revolutions, in (-1, 0]
  s = __builtin_amdgcn_sinf(rev);
  c = __builtin_amdgcn_cosf(rev);
#else
  float ang = (float)idx * (-6.283185307179586f / 2048.0f);
  __sincosf(ang, &s, &c);
#endif
}

template <bool INV>
__device__ __forceinline__ void dft8(float* xr, float* xi) {
  const float sg = INV ? -1.f : 1.f;
  const float c = 0.70710678118654752440f;
  float s0r = xr[0] + xr[4], s0i = xi[0] + xi[4];
  float s1r = xr[0] - xr[4], s1i = xi[0] - xi[4];
  float s2r = xr[2] + xr[6], s2i = xi[2] + xi[6];
  float s3r = xr[2] - xr[6], s3i = xi[2] - xi[6];
  float E0r = s0r + s2r, E0i = s0i + s2i;
  float E2r = s0r - s2r, E2i = s0i - s2i;
  float E1r = s1r + sg * s3i, E1i = s1i - sg * s3r;
  float E3r = s1r - sg * s3i, E3i = s1i + sg * s3r;
  float u0r = xr[1] + xr[5], u0i = xi[1] + xi[5];
  float u1r = xr[1] - xr[5], u1i = xi[1] - xi[5];
  float u2r = xr[3] + xr[7], u2i = xi[3] + xi[7];
  float u3r = xr[3] - xr[7], u3i = xi[3] - xi[7];
  float O0r = u0r + u2r, O0i = u0i + u2i;
  float O2r = u0r - u2r, O2i = u0i - u2i;
  float O1r = u1r + sg * u3i, O1i = u1i - sg * u3r;
  float O3r = u1r - sg * u3i, O3i = u1i + sg * u3r;
  float G0r = O0r, G0i = O0i;
  float G1r = O1r * c + O1i * (sg * c), G1i = O1i * c - O1r * (sg * c);
  float G2r = sg * O2i, G2i = -sg * O2r;
  float G3r = -O3r * c + O3i * (sg * c), G3i = -O3i * c - O3r * (sg * c);
  xr[0] = E0r + G0r; xi[0] = E0i + G0i;
  xr[1] = E1r + G1r; xi[1] = E1i + G1i;
  xr[2] = E2r + G2r; xi[2] = E2i + G2i;
  xr[3] = E3r + G3r; xi[3] = E3i + G3i;
  xr[4] = E0r - G0r; xi[4] = E0i - G0i;
  xr[5] = E1r - G1r; xi[5] = E1i - G1i;
  xr[6] = E2r - G2r; xi[6] = E2i - G2i;
  xr[7] = E3r - G3r; xi[7] = E3i - G3i;
}

template <bool INV>
__device__ __forceinline__ void dft4(float* xr, float* xi) {
  const float sg = INV ? -1.f : 1.f;
  float s0r = xr[0] + xr[2], s0i = xi[0] + xi[2];
  float s1r = xr[0] - xr[2], s1i = xi[0] - xi[2];
  float s2r = xr[1] + xr[3], s2i = xi[1] + xi[3];
  float s3r = xr[1] - xr[3], s3i = xi[1] - xi[3];
  xr[0] = s0r + s2r;        xi[0] = s0i + s2i;
  xr[1] = s1r + sg * s3i;   xi[1] = s1i - sg * s3r;
  xr[2] = s0r - s2r;        xi[2] = s0i - s2i;
  xr[3] = s1r - sg * s3i;   xi[3] = s1i + sg * s3r;
}

// In-place Stockham radix-8 stage on interleaved complex LDS buffer.
// Twiddles: one sincos for W^(s*p), then complex recurrence for powers.
template <bool INV>
__device__ __forceinline__ void stage8_ip(float2* CB, int s, int sLog, int t) {
  float ar[8], ai[8];
#pragma unroll
  for (int r = 0; r < 8; ++r) {
    float2 v = CB[PC(t + 256 * r)];
    ar[r] = v.x; ai[r] = v.y;
  }
  __syncthreads();
  dft8<INV>(ar, ai);
  int q = t & (s - 1), p = t >> sLog;
  int ob = q + 8 * s * p;
  float c1, s1; sincos_tw(s * p, c1, s1);
  if (INV) s1 = -s1;
  CB[PC(ob)] = make_float2(ar[0], ai[0]);
  float wc = c1, wsn = s1;
#pragma unroll
  for (int j = 1; j < 8; ++j) {
    float zr = ar[j] * wc - ai[j] * wsn;
    float zi = ar[j] * wsn + ai[j] * wc;
    CB[PC(ob + s * j)] = make_float2(zr, zi);
    if (j < 7) {
      float nc = wc * c1 - wsn * s1;
      wsn = wc * s1 + wsn * c1;
      wc = nc;
    }
  }
  __syncthreads();
}

// ---------------- transpose kernels (64x64 LDS tiles, float4 global) --------

__global__ __launch_bounds__(256) void ktrans_qk(const float* __restrict__ Q,
                                                 const float* __restrict__ K,
                                                 float2* __restrict__ ZT) {
  int bh = blockIdx.x >> 5, l0 = (blockIdx.x & 31) * 64;
  __shared__ float sq[64][65], sk[64][65];
  int t = threadIdx.x;
  const float4* Qb = (const float4*)(Q + ((size_t)bh * LEN + l0) * NE);
  const float4* Kb = (const float4*)(K + ((size_t)bh * LEN + l0) * NE);
  int x = t & 15, c4 = x * 4;
#pragma unroll
  for (int it = 0; it < 4; ++it) {
    int row = (t >> 4) + it * 16;
    float4 q4 = Qb[row * 16 + x];
    float4 k4 = Kb[row * 16 + x];
    sq[row][c4 + 0] = q4.x; sq[row][c4 + 1] = q4.y;
    sq[row][c4 + 2] = q4.z; sq[row][c4 + 3] = q4.w;
    sk[row][c4 + 0] = k4.x; sk[row][c4 + 1] = k4.y;
    sk[row][c4 + 2] = k4.z; sk[row][c4 + 3] = k4.w;
  }
  __syncthreads();
  float2* Zb = ZT + (size_t)bh * NE * LEN + l0;
  int l2 = (t & 31) * 2;
#pragma unroll
  for (int it = 0; it < 8; ++it) {
    int e = (t >> 5) + it * 8;
    float4 o;
    o.x = sq[l2][e];     o.y = sk[l2][e];
    o.z = sq[l2 + 1][e]; o.w = sk[l2 + 1][e];
    *(float4*)&Zb[(size_t)e * LEN + l2] = o;
  }
}

__global__ __launch_bounds__(256) void ktrans_v(const float* __restrict__ src,
                                                float* __restrict__ dst) {
  int bh = blockIdx.x >> 5, l0 = (blockIdx.x & 31) * 64;
  __shared__ float sT[64][65];
  int t = threadIdx.x;
  const float4* Sb = (const float4*)(src + ((size_t)bh * LEN + l0) * NE);
  int x = t & 15, c4 = x * 4;
#pragma unroll
  for (int it = 0; it < 4; ++it) {
    int row = (t >> 4) + it * 16;
    float4 v4 = Sb[row * 16 + x];
    sT[row][c4 + 0] = v4.x; sT[row][c4 + 1] = v4.y;
    sT[row][c4 + 2] = v4.z; sT[row][c4 + 3] = v4.w;
  }
  __syncthreads();
  float* Db = dst + (size_t)bh * NE * LEN + l0;
  int l4 = x * 4;
#pragma unroll
  for (int it = 0; it < 4; ++it) {
    int e = (t >> 4) + it * 16;
    float4 o;
    o.x = sT[l4 + 0][e]; o.y = sT[l4 + 1][e];
    o.z = sT[l4 + 2][e]; o.w = sT[l4 + 3][e];
    *(float4*)&Db[(size_t)e * LEN + l4] = o;
  }
}

__global__ __launch_bounds__(256) void ktrans_o(const float* __restrict__ OT,
                                                float* __restrict__ out) {
  int bh = blockIdx.x >> 5, l0 = (blockIdx.x & 31) * 64;
  __shared__ float sT[64][65];  // [e][l]
  int t = threadIdx.x;
  const float* Sb = OT + (size_t)bh * NE * LEN + l0;
  int x = t & 15, l4 = x * 4;
#pragma unroll
  for (int it = 0; it < 4; ++it) {
    int e = (t >> 4) + it * 16;
    float4 v4 = *(const float4*)&Sb[(size_t)e * LEN + l4];
    sT[e][l4 + 0] = v4.x; sT[e][l4 + 1] = v4.y;
    sT[e][l4 + 2] = v4.z; sT[e][l4 + 3] = v4.w;
  }
  __syncthreads();
  float* Ob = out + ((size_t)bh * LEN + l0) * NE;
  int e4 = x * 4;
#pragma unroll
  for (int it = 0; it < 4; ++it) {
    int row = (t >> 4) + it * 16;
    float4 o;
    o.x = sT[e4 + 0][row]; o.y = sT[e4 + 1][row];
    o.z = sT[e4 + 2][row]; o.w = sT[e4 + 3][row];
    *(float4*)&Ob[row * NE + e4] = o;
  }
}

// ---------------- FFT + corr + topk + softmax ----------------

__global__ __launch_bounds__(256) void kfft(const float2* __restrict__ ZT,
                                            float* __restrict__ Wt,
                                            int* __restrict__ Dl) {
  __shared__ float2 CB[2176];            // 2048 complex + pad (17.4 KB)
  __shared__ float mv[64]; __shared__ int mi[64];
  const int t = threadIdx.x;
  const int wv = t >> 6, ln = t & 63;
  const float2* z = ZT + (size_t)blockIdx.x * LEN;

  // ---- forward stage 1 (s=1): global -> LDS scatter ----
  {
    float ar[8], ai[8];
#pragma unroll
    for (int r = 0; r < 8; ++r) {
      float2 v = z[t + 256 * r];
      ar[r] = v.x; ai[r] = v.y;
    }
    dft8<false>(ar, ai);
    float c1, s1; sincos_tw(t, c1, s1);
    CB[PC(8 * t)] = make_float2(ar[0], ai[0]);
    float wc = c1, wsn = s1;
#pragma unroll
    for (int j = 1; j < 8; ++j) {
      float zr = ar[j] * wc - ai[j] * wsn;
      float zi = ar[j] * wsn + ai[j] * wc;
      CB[PC(8 * t + j)] = make_float2(zr, zi);
      if (j < 7) {
        float nc = wc * c1 - wsn * s1;
        wsn = wc * s1 + wsn * c1;
        wc = nc;
      }
    }
  }
  __syncthreads();
  stage8_ip<false>(CB, 8, 3, t);
  stage8_ip<false>(CB, 64, 6, t);
  // ---- forward radix-4 (s=512, no twiddle): thread-private slots ----
#pragma unroll
  for (int h = 0; h < 2; ++h) {
    int u = t + 256 * h;
    float xr[4], xi[4];
#pragma unroll
    for (int r = 0; r < 4; ++r) {
      float2 v = CB[PC(u + 512 * r)];
      xr[r] = v.x; xi[r] = v.y;
    }
    dft4<false>(xr, xi);
#pragma unroll
    for (int j = 0; j < 4; ++j) CB[PC(u + 512 * j)] = make_float2(xr[j], xi[j]);
  }
  __syncthreads();

  // ---- spectrum: C = X*conj(Y), pair-based (f in [0,1024), m = 2048-f) ----
  {
    float2 zf[4], zm[4];
#pragma unroll
    for (int r = 0; r < 4; ++r) {
      int f = t + 256 * r;
      int m = (LEN - f) & (LEN - 1);
      zf[r] = CB[PC(f)]; zm[r] = CB[PC(m)];
    }
    float2 e1 = make_float2(0.f, 0.f);
    if (t == 0) e1 = CB[PC(1024)];
    __syncthreads();
#pragma unroll
    for (int r = 0; r < 4; ++r) {
      int f = t + 256 * r;
      int m = (LEN - f) & (LEN - 1);
      float Xr = 0.5f * (zf[r].x + zm[r].x), Xi = 0.5f * (zf[r].y - zm[r].y);
      float Yr = 0.5f * (zf[r].y + zm[r].y), Yi = -0.5f * (zf[r].x - zm[r].x);
      CB[PC(f)] = make_float2(Xr * Yr + Xi * Yi, Xi * Yr - Xr * Yi);
      float Xr2 = 0.5f * (zm[r].x + zf[r].x), Xi2 = 0.5f * (zm[r].y - zf[r].y);
      float Yr2 = 0.5f * (zf[r].y + zm[r].y), Yi2 = -0.5f * (zm[r].x - zf[r].x);
      CB[PC(m)] = make_float2(Xr2 * Yr2 + Xi2 * Yi2, Xi2 * Yr2 - Xr2 * Yi2);
    }
    if (t == 0) CB[PC(1024)] = make_float2(e1.x * e1.y, 0.f);
  }
  __syncthreads();

  // ---- inverse FFT: 3 in-place radix-8 stages + final radix-4 into regs ----
  stage8_ip<true>(CB, 1, 0, t);
  stage8_ip<true>(CB, 8, 3, t);
  stage8_ip<true>(CB, 64, 6, t);
  float rv[8]; int ri[8];
#pragma unroll
  for (int h = 0; h < 2; ++h) {
    int u = t + 256 * h;
    float xr[4], xi[4];
#pragma unroll
    for (int r = 0; r < 4; ++r) {
      float2 v = CB[PC(u + 512 * r)];
      xr[r] = v.x; xi[r] = v.y;
    }
    dft4<true>(xr, xi);
#pragma unroll
    for (int j = 0; j < 4; ++j) {
      rv[h * 4 + j] = xr[j];          // corr * 2048
      ri[h * 4 + j] = u + 512 * j;    // lag index
    }
  }

  // ---- per-lane Batcher sort-8 (desc by value) ----
#define CE(i, j) { bool sw = rv[i] < rv[j];                                   \
    float tv = sw ? rv[j] : rv[i]; rv[j] = sw ? rv[i] : rv[j]; rv[i] = tv;    \
    int tx = sw ? ri[j] : ri[i];  ri[j] = sw ? ri[i] : ri[j];  ri[i] = tx; }
  CE(0,1) CE(2,3) CE(4,5) CE(6,7)
  CE(0,2) CE(1,3) CE(4,6) CE(5,7)
  CE(1,2) CE(5,6)
  CE(0,4) CE(1,5) CE(2,6) CE(3,7)
  CE(2,4) CE(3,5)
  CE(1,2) CE(3,4) CE(5,6)
#undef CE

  // ---- per-wave top-15: head-pop tournament ----
  for (int it = 0; it < TOPK; ++it) {
    float bv = rv[0]; int bidx = ri[0];
#pragma unroll
    for (int off = 32; off >= 1; off >>= 1) {
      float ov = __shfl_xor(bv, off);
      int oi = __shfl_xor(bidx, off);
      bool btr = (ov > bv) || (ov == bv && oi < bidx);
      if (btr) { bv = ov; bidx = oi; }
    }
    if (ln == 0) { mv[wv * 16 + it] = bv; mi[wv * 16 + it] = bidx; }
    if (bidx == ri[0]) {  // this lane's head won (indices globally unique)
#pragma unroll
      for (int k = 0; k < 7; ++k) { rv[k] = rv[k + 1]; ri[k] = ri[k + 1]; }
      rv[7] = NINF;
    }
  }
  __syncthreads();

  // ---- single-wave merge of 4x15 + softmax, all in registers ----
  if (wv == 0) {
    float v = ((ln & 15) < TOPK) ? mv[ln] : NINF;
    int ix = ((ln & 15) < TOPK) ? mi[ln] : 0;
    float myv = NINF; int myi = 0;
    for (int it = 0; it < TOPK; ++it) {
      float bv = v; int bidx = ix;
#pragma unroll
      for (int off = 32; off >= 1; off >>= 1) {
        float ov = __shfl_xor(bv, off);
        int oi = __shfl_xor(bidx, off);
        bool btr = (ov > bv) || (ov == bv && oi < bidx);
        if (btr) { bv = ov; bidx = oi; }
      }
      if (ln == it) { myv = bv; myi = bidx; }
      if (ix == bidx) v = NINF;
    }
    const float scl = 1.0f / 2048.0f;
    float vmax = __shfl(myv, 0);  // first selected == max
    float e = (ln < TOPK) ? expf((myv - vmax) * scl) : 0.f;
    float ssum = e;
#pragma unroll
    for (int off = 1; off < 16; off <<= 1) ssum += __shfl_xor(ssum, off);
    if (ln < TOPK) {
      Wt[(size_t)blockIdx.x * 16 + ln] = e / ssum;
      Dl[(size_t)blockIdx.x * 16 + ln] = myi;
    }
  }
}

// ---------------- weighted circular gather (coalesced OT write) -------------

__global__ __launch_bounds__(256) void kgather(const float* __restrict__ VT,
                                               const float* __restrict__ Wt,
                                               const int* __restrict__ Dl,
                                               float* __restrict__ OT) {
  __shared__ float v[LEN];
  const int t = threadIdx.x;
  const int series = blockIdx.x;
  const float4* src = (const float4*)(VT + (size_t)series * LEN);
  float4* vv = (float4*)v;
#pragma unroll
  for (int i = 0; i < 2; ++i) vv[t + 256 * i] = src[t + 256 * i];
  float w[TOPK]; int d[TOPK];
#pragma unroll
  for (int i = 0; i < TOPK; ++i) {
    w[i] = Wt[(size_t)series * 16 + i];
    d[i] = Dl[(size_t)series * 16 + i];
  }
  __syncthreads();
  float* dst = OT + (size_t)series * LEN;
#pragma unroll
  for (int r = 0; r < 8; ++r) {
    int l = t + 256 * r;
    float acc = 0.f;
#pragma unroll
    for (int i = 0; i < TOPK; ++i) acc += w[i] * v[(l + d[i]) & (LEN - 1)];
    dst[l] = acc;
  }
}

extern "C" void kernel_launch(void* const* d_in, const int* in_sizes, int n_in,
                              void* d_out, int out_size, void* d_ws, size_t ws_size,
                              hipStream_t stream) {
  const float* Q = (const float*)d_in[0];
  const float* K = (const float*)d_in[1];
  const float* V = (const float*)d_in[2];
  float* out = (float*)d_out;
  char* ws = (char*)d_ws;

  const size_t ZT_BYTES = (size_t)NSER * LEN * sizeof(float2);  // 256 MiB
  float2* ZT = (float2*)ws;
  float* Wt = (float*)(ws + ZT_BYTES);
  int* Dl = (int*)(ws + ZT_BYTES + (size_t)NSER * 16 * sizeof(float));
  float* VT = out;          // d_out as scratch for transposed V
  float* OT = (float*)ws;   // aliases ZT (dead after kfft)

  ktrans_qk<<<BH * 32, 256, 0, stream>>>(Q, K, ZT);
  kfft<<<NSER, 256, 0, stream>>>(ZT, Wt, Dl);
  ktrans_v<<<BH * 32, 256, 0, stream>>>(V, VT);
  kgather<<<NSER, 256, 0, stream>>>(VT, Wt, Dl, OT);
  ktrans_o<<<BH * 32, 256, 0, stream>>>(OT, out);
}